// Round 1
// baseline (171.819 us; speedup 1.0000x reference)
//
#include <hip/hip_runtime.h>

#define NGRID 16
#define NCELL 4096

__device__ __forceinline__ int cell_of(float x0, float x1, float x2) {
    int i0 = (int)(x0 / 0.1875f + 8.0f);
    int i1 = (int)(x1 / 0.1875f + 8.0f);
    int i2 = (int)(x2 / 0.1875f + 8.0f);
    i0 = i0 < 0 ? 0 : (i0 > 15 ? 15 : i0);
    i1 = i1 < 0 ? 0 : (i1 > 15 ? 15 : i1);
    i2 = i2 < 0 ? 0 : (i2 > 15 ? 15 : i2);
    return (i0 * 16 + i1) * 16 + i2;
}

// Kernel 1: count active points per cell; write zeros for masked points.
__global__ void k_count(const float* __restrict__ xs, int* __restrict__ counts,
                        float* __restrict__ out, int P) {
    int p = blockIdx.x * blockDim.x + threadIdx.x;
    if (p >= P) return;
    float x0 = xs[p * 3 + 0], x1 = xs[p * 3 + 1], x2 = xs[p * 3 + 2];
    bool m = (fabsf(x0) < 1.5f) && (fabsf(x1) < 1.5f) && (fabsf(x2) < 1.5f);
    if (m) {
        atomicAdd(&counts[cell_of(x0, x1, x2)], 1);
    } else {
        out[p * 3 + 0] = 0.0f;
        out[p * 3 + 1] = 0.0f;
        out[p * 3 + 2] = 0.0f;
        out[3 * P + p] = 0.0f;
    }
}

// Kernel 2: exclusive prefix sum over 4096 cell counts. One wave (64 lanes),
// each lane owns 64 consecutive cells.
__global__ void k_scan(const int* __restrict__ counts, int* __restrict__ offsets,
                       int* __restrict__ cursor) {
    int l = threadIdx.x;
    int base = l * 64;
    int s = 0;
    for (int k = 0; k < 64; k++) s += counts[base + k];
    int incl = s;
    for (int d = 1; d < 64; d <<= 1) {
        int v = __shfl_up(incl, d, 64);
        if (l >= d) incl += v;
    }
    int run = incl - s;  // exclusive prefix of this lane's chunk
    for (int k = 0; k < 64; k++) {
        offsets[base + k] = run;
        cursor[base + k] = run;
        run += counts[base + k];
    }
    if (l == 63) offsets[4096] = run;
}

// Kernel 3: scatter active point indices into per-cell contiguous ranges.
__global__ void k_scatter(const float* __restrict__ xs, int* __restrict__ cursor,
                          int* __restrict__ sorted, int P) {
    int p = blockIdx.x * blockDim.x + threadIdx.x;
    if (p >= P) return;
    float x0 = xs[p * 3 + 0], x1 = xs[p * 3 + 1], x2 = xs[p * 3 + 2];
    bool m = (fabsf(x0) < 1.5f) && (fabsf(x1) < 1.5f) && (fabsf(x2) < 1.5f);
    if (!m) return;
    int c = cell_of(x0, x1, x2);
    int pos = atomicAdd(&cursor[c], 1);
    sorted[pos] = p;
}

// Kernel 4: one block (1 wave) per cell. Weights are wave-uniform -> scalar
// loads. Per-lane activations live in LDS (dynamically indexed); accumulators
// in registers (fully unrolled output loops).
__global__ void __launch_bounds__(64) k_mlp(
    const float* __restrict__ xs, const float* __restrict__ dvs,
    const float* __restrict__ w1, const float* __restrict__ b1,
    const float* __restrict__ w2, const float* __restrict__ b2,
    const float* __restrict__ w3, const float* __restrict__ b3,
    const float* __restrict__ w4, const float* __restrict__ b4,
    const float* __restrict__ w5, const float* __restrict__ b5,
    const int* __restrict__ offsets, const int* __restrict__ sorted,
    float* __restrict__ out, int P) {
    __shared__ float buf[64 * 63];  // per-thread 63-float activation slot, stride 63 -> conflict-free
    int cell = blockIdx.x;
    int start = offsets[cell], end = offsets[cell + 1];
    if (start >= end) return;

    const float* W1 = w1 + (size_t)cell * 2016;  // 63x32
    const float* B1 = b1 + cell * 32;
    const float* W2 = w2 + (size_t)cell * 1056;  // 32x33
    const float* B2 = b2 + cell * 33;
    const float* W3 = w3 + (size_t)cell * 1024;  // 32x32
    const float* B3 = b3 + cell * 32;
    const float* W4 = w4 + (size_t)cell * 1888;  // 59x32
    const float* B4 = b4 + cell * 32;
    const float* W5 = w5 + (size_t)cell * 96;    // 32x3
    const float* B5 = b5 + cell * 3;

    float* my = buf + threadIdx.x * 63;

    for (int t0 = start; t0 < end; t0 += 64) {
        int t = t0 + threadIdx.x;
        bool valid = t < end;
        int idx = sorted[valid ? t : start];

        float x0 = xs[idx * 3 + 0], x1 = xs[idx * 3 + 1], x2 = xs[idx * 3 + 2];

        // positional encoding (63) into LDS
        my[0] = x0; my[1] = x1; my[2] = x2;
        float pw = 1.0f;
#pragma unroll
        for (int j = 0; j < 10; j++) {
            float a0 = pw * x0, a1 = pw * x1, a2 = pw * x2;
            my[3 + 6 * j + 0] = __sinf(a0);
            my[3 + 6 * j + 1] = __sinf(a1);
            my[3 + 6 * j + 2] = __sinf(a2);
            my[6 + 6 * j + 0] = __cosf(a0);
            my[6 + 6 * j + 1] = __cosf(a1);
            my[6 + 6 * j + 2] = __cosf(a2);
            pw *= 2.0f;
        }

        float h[33];
        // ---- layer 1: 63 -> 32, relu
#pragma unroll
        for (int o = 0; o < 32; o++) h[o] = B1[o];
#pragma unroll 2
        for (int i = 0; i < 63; i++) {
            float e = my[i];
            const float* wr = W1 + i * 32;
#pragma unroll
            for (int o = 0; o < 32; o++) h[o] = fmaf(e, wr[o], h[o]);
        }
#pragma unroll
        for (int o = 0; o < 32; o++) my[o] = fmaxf(h[o], 0.0f);

        // ---- layer 2: 32 -> 33, relu; out[0] = sigma
        float g[33];
#pragma unroll
        for (int o = 0; o < 33; o++) g[o] = B2[o];
#pragma unroll 2
        for (int i = 0; i < 32; i++) {
            float e = my[i];
            const float* wr = W2 + i * 33;
#pragma unroll
            for (int o = 0; o < 33; o++) g[o] = fmaf(e, wr[o], g[o]);
        }
        float sigma = fmaxf(g[0], 0.0f);
#pragma unroll
        for (int o = 0; o < 32; o++) my[o] = fmaxf(g[o + 1], 0.0f);

        // ---- layer 3: 32 -> 32, NO activation
#pragma unroll
        for (int o = 0; o < 32; o++) h[o] = B3[o];
#pragma unroll 2
        for (int i = 0; i < 32; i++) {
            float e = my[i];
            const float* wr = W3 + i * 32;
#pragma unroll
            for (int o = 0; o < 32; o++) h[o] = fmaf(e, wr[o], h[o]);
        }
#pragma unroll
        for (int o = 0; o < 32; o++) my[o] = h[o];

        // ---- direction encoding (27) into my[32..58]
        float d0 = dvs[idx * 3 + 0], d1 = dvs[idx * 3 + 1], d2 = dvs[idx * 3 + 2];
        my[32] = d0; my[33] = d1; my[34] = d2;
        pw = 1.0f;
#pragma unroll
        for (int j = 0; j < 4; j++) {
            float a0 = pw * d0, a1 = pw * d1, a2 = pw * d2;
            my[35 + 6 * j + 0] = __sinf(a0);
            my[35 + 6 * j + 1] = __sinf(a1);
            my[35 + 6 * j + 2] = __sinf(a2);
            my[38 + 6 * j + 0] = __cosf(a0);
            my[38 + 6 * j + 1] = __cosf(a1);
            my[38 + 6 * j + 2] = __cosf(a2);
            pw *= 2.0f;
        }

        // ---- layer 4: 59 -> 32, relu
#pragma unroll
        for (int o = 0; o < 32; o++) h[o] = B4[o];
#pragma unroll 2
        for (int i = 0; i < 59; i++) {
            float e = my[i];
            const float* wr = W4 + i * 32;
#pragma unroll
            for (int o = 0; o < 32; o++) h[o] = fmaf(e, wr[o], h[o]);
        }
#pragma unroll
        for (int o = 0; o < 32; o++) my[o] = fmaxf(h[o], 0.0f);

        // ---- layer 5: 32 -> 3, sigmoid
        float c0 = B5[0], c1 = B5[1], c2 = B5[2];
#pragma unroll 4
        for (int i = 0; i < 32; i++) {
            float e = my[i];
            c0 = fmaf(e, W5[i * 3 + 0], c0);
            c1 = fmaf(e, W5[i * 3 + 1], c1);
            c2 = fmaf(e, W5[i * 3 + 2], c2);
        }

        if (valid) {
            out[idx * 3 + 0] = 1.0f / (1.0f + __expf(-c0));
            out[idx * 3 + 1] = 1.0f / (1.0f + __expf(-c1));
            out[idx * 3 + 2] = 1.0f / (1.0f + __expf(-c2));
            out[3 * P + idx] = sigma;
        }
    }
}

extern "C" void kernel_launch(void* const* d_in, const int* in_sizes, int n_in,
                              void* d_out, int out_size, void* d_ws, size_t ws_size,
                              hipStream_t stream) {
    const float* xs = (const float*)d_in[0];
    const float* dv = (const float*)d_in[1];
    const float* w1 = (const float*)d_in[2];
    const float* b1 = (const float*)d_in[3];
    const float* w2 = (const float*)d_in[4];
    const float* b2 = (const float*)d_in[5];
    const float* w3 = (const float*)d_in[6];
    const float* b3 = (const float*)d_in[7];
    const float* w4 = (const float*)d_in[8];
    const float* b4 = (const float*)d_in[9];
    const float* w5 = (const float*)d_in[10];
    const float* b5 = (const float*)d_in[11];
    float* out = (float*)d_out;
    int P = in_sizes[0] / 3;

    // ws layout (ints): counts[4096] | offsets[4104 incl pad, uses 4097] | cursor[4096] | sorted[P]
    int* counts = (int*)d_ws;
    int* offsets = counts + 4096;
    int* cursor = offsets + 4104;
    int* sorted = cursor + 4096;

    hipMemsetAsync(counts, 0, 4096 * sizeof(int), stream);

    int blk = 256;
    int grd = (P + blk - 1) / blk;
    k_count<<<grd, blk, 0, stream>>>(xs, counts, out, P);
    k_scan<<<1, 64, 0, stream>>>(counts, offsets, cursor);
    k_scatter<<<grd, blk, 0, stream>>>(xs, cursor, sorted, P);
    k_mlp<<<NCELL, 64, 0, stream>>>(xs, dv, w1, b1, w2, b2, w3, b3, w4, b4, w5, b5,
                                    offsets, sorted, out, P);
}